// Round 14
// baseline (181.523 us; speedup 1.0000x reference)
//
#include <hip/hip_runtime.h>
#include <hip/hip_bf16.h>

typedef short short8 __attribute__((ext_vector_type(8)));
typedef float f32x4 __attribute__((ext_vector_type(4)));
typedef unsigned int uint4v __attribute__((ext_vector_type(4)));

typedef const __attribute__((address_space(1))) unsigned int* gas_ptr;
typedef __attribute__((address_space(3))) unsigned int* las_ptr;
// async global->LDS, 16B/lane; LDS dest = wave-uniform base + lane*16 (m97/m104)
#define ASYNC16(g, l) __builtin_amdgcn_global_load_lds((gas_ptr)(g), (las_ptr)(l), 16, 0, 0)

__device__ __forceinline__ unsigned short f2bf(float f) {
    unsigned int u = __builtin_bit_cast(unsigned int, f);
    u += 0x7fff + ((u >> 16) & 1);   // RNE
    return (unsigned short)(u >> 16);
}
__device__ __forceinline__ float bf2f(unsigned short s) {
    unsigned int u = (unsigned int)s << 16;
    return __builtin_bit_cast(float, u);
}
__device__ __forceinline__ unsigned int pkbf_trunc(float lo, float hi) {
    return __builtin_amdgcn_perm(__builtin_bit_cast(unsigned int, hi),
                                 __builtin_bit_cast(unsigned int, lo), 0x07060302u);
}
__device__ __forceinline__ float fexp2(float x) {
#if __has_builtin(__builtin_amdgcn_exp2f)
    return __builtin_amdgcn_exp2f(x);
#else
    return __expf(x * 0.6931471805599453f);
#endif
}

// ---------------------------------------------------------------- fused prep (r10):
// blocks [0,4096): cast x->bf16 ; [4096,4864): transpose w_qkv ; [4864,5120): transpose w_out
// (no XCD swizzle: elementwise, no cross-block reuse — T1 measured-null on such ops)
__device__ __forceinline__ void transpose_tile(
    const float* __restrict__ w, unsigned short* __restrict__ wt,
    int K, int N, int k0, int n0, unsigned short* tile)
{
    for (int i = threadIdx.x; i < 64 * 64; i += 256) {
        int r = i >> 6, c = i & 63;
        tile[r * 65 + c] = f2bf(w[(size_t)(k0 + r) * N + n0 + c]);
    }
    __syncthreads();
    for (int i = threadIdx.x; i < 64 * 64; i += 256) {
        int r = i >> 6, c = i & 63;
        wt[(size_t)(n0 + r) * K + k0 + c] = tile[c * 65 + r];
    }
}

__global__ __launch_bounds__(256) void prep(
    const float* __restrict__ x, const float* __restrict__ w_qkv,
    const float* __restrict__ w_out,
    unsigned short* __restrict__ x_b, unsigned short* __restrict__ wqkv_t,
    unsigned short* __restrict__ wout_t)
{
    __shared__ unsigned short tile[64 * 65];
    int bid = blockIdx.x;
    if (bid < 4096) {
        int i = (bid * 256 + threadIdx.x) * 4;
        float4 v = *(const float4*)(x + i);
        ushort4 o;
        o.x = f2bf(v.x); o.y = f2bf(v.y); o.z = f2bf(v.z); o.w = f2bf(v.w);
        *(ushort4*)(x_b + i) = o;
    } else if (bid < 4096 + 768) {
        int t = bid - 4096;
        transpose_tile(w_qkv, wqkv_t, 1024, 3072, (t / 48) * 64, (t % 48) * 64, tile);
    } else {
        int t = bid - 4864;
        transpose_tile(w_out, wout_t, 1024, 1024, (t >> 4) * 64, (t & 15) * 64, tile);
    }
}

// ---------------------------------------------------------------- GEMM: C = A * Bt^T + bias
// m97 structure, BK=64 via twin 8KB panels (r4: verified-good).
// Round-14: + T1 bijective XCD swizzle (grids 768/256, both %8==0). Without it,
// an XCD's ~96 scattered blocks touch ~24 B-panels (6 MB > 4 MB L2); contiguous
// chunks touch 3 (768 KB L2-resident). Pure index remap — no schedule change
// (r11/r12 lesson: leave the staging paths alone).
// QKV mode: cols [0,2048) -> qkv (stride 2048); cols [2048,3072) -> vT

template<bool OUT_BF16, bool QKV>
__global__ __launch_bounds__(256, 3) void gemm_bt(
    const unsigned short* __restrict__ A,
    const unsigned short* __restrict__ Bt,
    const float* __restrict__ bias,
    void* __restrict__ C,
    unsigned short* __restrict__ vTp,
    int M, int N, int K)
{
    __shared__ __align__(16) unsigned short As[2][128 * 32];
    __shared__ __align__(16) unsigned short Bs[2][128 * 32];
    const int tid = threadIdx.x;
    const int lane = tid & 63;
    const int wave = tid >> 6;
    const int wr = wave >> 1, wc = wave & 1;

    // T1: bijective XCD swizzle (nwg % 8 == 0 for both instantiations)
    const int nwg = gridDim.x * gridDim.y;
    const int bid = blockIdx.x + gridDim.x * blockIdx.y;
    const int swz = (bid & 7) * (nwg >> 3) + (bid >> 3);
    const int m0 = (swz % gridDim.x) * 128, n0 = (swz / gridDim.x) * 128;
    const int fr = lane & 15, fq = lane >> 4;

    f32x4 acc[4][4] = {};

    const int grow = lane >> 2;
    const int gcol = (lane & 3) * 8;
    const unsigned short* Ag = A  + (size_t)(m0 + wave * 32 + grow) * K + gcol;
    const unsigned short* Bg = Bt + (size_t)(n0 + wave * 32 + grow) * K + gcol;
    const int wb0 = (wave * 32) * 32;
    const int wb1 = (wave * 32 + 16) * 32;

    for (int k0 = 0; k0 < K; k0 += 64) {
        __syncthreads();
        ASYNC16(Ag + k0,               As[0] + wb0);
        ASYNC16(Ag + 16 * K + k0,      As[0] + wb1);
        ASYNC16(Bg + k0,               Bs[0] + wb0);
        ASYNC16(Bg + 16 * K + k0,      Bs[0] + wb1);
        ASYNC16(Ag + k0 + 32,          As[1] + wb0);
        ASYNC16(Ag + 16 * K + k0 + 32, As[1] + wb1);
        ASYNC16(Bg + k0 + 32,          Bs[1] + wb0);
        ASYNC16(Bg + 16 * K + k0 + 32, Bs[1] + wb1);
        __syncthreads();

#pragma unroll
        for (int h = 0; h < 2; h++) {
            short8 af[4], bfr[4];
#pragma unroll
            for (int i = 0; i < 4; i++)
                af[i] = *(const short8*)(As[h] + (wr * 64 + i * 16 + fr) * 32 + fq * 8);
#pragma unroll
            for (int j = 0; j < 4; j++)
                bfr[j] = *(const short8*)(Bs[h] + (wc * 64 + j * 16 + fr) * 32 + fq * 8);
#pragma unroll
            for (int i = 0; i < 4; i++)
#pragma unroll
                for (int j = 0; j < 4; j++)
                    acc[i][j] = __builtin_amdgcn_mfma_f32_16x16x32_bf16(af[i], bfr[j], acc[i][j], 0, 0, 0);
        }
    }

#pragma unroll
    for (int i = 0; i < 4; i++)
#pragma unroll
        for (int j = 0; j < 4; j++) {
            int col = n0 + wc * 64 + j * 16 + fr;
            float bv = bias[col];
            if (QKV && col >= 2048) {
                int hh = (col - 2048) >> 6, d = col & 63;
#pragma unroll
                for (int r = 0; r < 4; r++) {
                    int row = m0 + wr * 64 + i * 16 + fq * 4 + r;
                    int bb = row >> 11, s = row & 2047;
                    vTp[((size_t)(bb * 16 + hh) * 64 + d) * 2048 + s] = f2bf(acc[i][j][r] + bv);
                }
            } else {
                const int cstride = QKV ? 2048 : N;
#pragma unroll
                for (int r = 0; r < 4; r++) {
                    int row = m0 + wr * 64 + i * 16 + fq * 4 + r;
                    float v = acc[i][j][r] + bv;
                    if (OUT_BF16)
                        ((unsigned short*)C)[(size_t)row * cstride + col] = f2bf(v);
                    else
                        ((float*)C)[(size_t)row * cstride + col] = v;
                }
            }
        }
}

// ---------------------------------------------------------------- flash attention (causal, NO key-split)
// Round-14 = round-13 (174.3 µs, passed) + T1 XCD swizzle (grid 512 % 8 == 0):
// a contiguous 64-block chunk covers 4 (b,h) groups -> 2 MB K/V L2-resident per
// XCD, vs the default round-robin touching all 32 groups' K/V.
// r13 structure (verified): each block covers ALL keys for its balanced q-tile
// pair {p, 31-p} (66 weighted units for every p); grid 512 = 2/CU, zero tail;
// in-register normalize, final attn written directly (no reduce_attn, no Opart).
// 4-wave 256-thread blocks, 64-key tile, 32 KB LDS, launch bound (256,2), T14
// async-STAGE split (+8% r10). Wave w owns 32 q-rows: rg0 = q-tile p rows
// [w*16,+16); rg1 = q-tile 31-p rows. Swapped QK^T (lane holds 4 consecutive keys
// of one q-row; P store = one b64), bijective P swizzle, K/V global-source
// pre-swizzle (rule #21), setprio, exp2-folded fixed-shift softmax p=exp(s/8-8).

template<int RG0>   // 0: both rg active; 1: only rg1 (jt > p)
__device__ __forceinline__ void attn_step(
    const unsigned short* __restrict__ Ks0, const unsigned short* __restrict__ Ks1,
    const unsigned short* __restrict__ Vs0, const unsigned short* __restrict__ Vs1,
    unsigned short* __restrict__ Psw,
    const short8 (&qf)[2][2], const short8 ones,
    f32x4 (&o_acc)[2][4], f32x4 (&l_acc)[2],
    int j0, int fr, int fq,
    const int (&qrow0)[2], bool diagA, bool diagB)
{
    const int kpos = ((fq + (fr >> 1)) & 3) * 8;   // K/V bank-position (matches staging swizzle)
    short8 kf[4][2];
#pragma unroll
    for (int t = 0; t < 4; t++) {
        kf[t][0] = *(const short8*)(Ks0 + (t * 16 + fr) * 32 + kpos);
        kf[t][1] = *(const short8*)(Ks1 + (t * 16 + fr) * 32 + kpos);
    }

    const float C1 = 0.18033688011112042f;   // 0.125 * log2(e)
    const float C2 = -11.541560327111707f;   // -8 * log2(e)

#pragma unroll
    for (int rg = RG0; rg < 2; rg++) {
        f32x4 s[4];
        __builtin_amdgcn_s_setprio(1);
#pragma unroll
        for (int t = 0; t < 4; t++) {
            s[t] = (f32x4){0.f, 0.f, 0.f, 0.f};
            s[t] = __builtin_amdgcn_mfma_f32_16x16x32_bf16(kf[t][0], qf[rg][0], s[t], 0, 0, 0);
            s[t] = __builtin_amdgcn_mfma_f32_16x16x32_bf16(kf[t][1], qf[rg][1], s[t], 0, 0, 0);
        }
        __builtin_amdgcn_s_setprio(0);
        const bool diag = (rg == 0) ? diagA : diagB;
        unsigned short* prow = Psw + rg * (16 * 64);
        const int qr = qrow0[rg] + fr;
        if (diag) {   // wave-uniform branch: mask cost only on diag tiles
#pragma unroll
            for (int t = 0; t < 4; t++) {
                const int kb = j0 + t * 16 + fq * 4;
                float p[4];
#pragma unroll
                for (int r = 0; r < 4; r++) {
                    float v = fexp2(s[t][r] * C1 + C2);
                    if (kb + r > qr) v = 0.f;
                    p[r] = v;
                }
                uint2 pk;
                pk.x = pkbf_trunc(p[0], p[1]);
                pk.y = pkbf_trunc(p[2], p[3]);
                const int blk = (t * 2 + (fq >> 1) + fr) & 7;
                *(uint2*)(prow + fr * 64 + blk * 8 + (fq & 1) * 4) = pk;
            }
        } else {
#pragma unroll
            for (int t = 0; t < 4; t++) {
                float p[4];
#pragma unroll
                for (int r = 0; r < 4; r++)
                    p[r] = fexp2(s[t][r] * C1 + C2);
                uint2 pk;
                pk.x = pkbf_trunc(p[0], p[1]);
                pk.y = pkbf_trunc(p[2], p[3]);
                const int blk = (t * 2 + (fq >> 1) + fr) & 7;
                *(uint2*)(prow + fr * 64 + blk * 8 + (fq & 1) * 4) = pk;
            }
        }
    }

    // O += P V ; l += P 1   (Psw wave-private: same-wave LDS ordering, no barrier)
#pragma unroll
    for (int ks = 0; ks < 2; ks++) {
        const unsigned short* Vsb = ks ? Vs1 : Vs0;
        const int colp = ((ks * 4 + fq + fr) & 7) * 8;   // P bank-position unswizzle
        short8 pf[2];
#pragma unroll
        for (int rg = RG0; rg < 2; rg++)
            pf[rg] = *(const short8*)(Psw + rg * (16 * 64) + fr * 64 + colp);
        __builtin_amdgcn_s_setprio(1);
#pragma unroll
        for (int t = 0; t < 4; t++) {
            short8 vf = *(const short8*)(Vsb + (t * 16 + fr) * 32 + kpos);
#pragma unroll
            for (int rg = RG0; rg < 2; rg++)
                o_acc[rg][t] = __builtin_amdgcn_mfma_f32_16x16x32_bf16(pf[rg], vf, o_acc[rg][t], 0, 0, 0);
        }
#pragma unroll
        for (int rg = RG0; rg < 2; rg++)
            l_acc[rg] = __builtin_amdgcn_mfma_f32_16x16x32_bf16(pf[rg], ones, l_acc[rg], 0, 0, 0);
        __builtin_amdgcn_s_setprio(0);
    }
}

__global__ __launch_bounds__(256, 2) void flash_attn(
    const unsigned short* __restrict__ qkv,   // (B*S, 2048): Q | K
    const unsigned short* __restrict__ vT,    // (B*16 heads, 64 dims, 2048 keys)
    unsigned short* __restrict__ attn)        // (B*S, 1024) final normalized O
{
    // T1: bijective XCD swizzle over the 512-block grid (16 p x 32 bh)
    const int bid = blockIdx.x + 16 * blockIdx.y;
    const int swz = (bid & 7) * 64 + (bid >> 3);
    const int p = swz & 15;                   // q-tile pair {p, 31-p}
    const int bh = swz >> 4;
    const int h = bh & 15, b = bh >> 4;
    const int tid = threadIdx.x, wave = tid >> 6, lane = tid & 63;
    const int fr = lane & 15, fq = lane >> 4;
    const size_t RS = 2048;

    const unsigned short* Qb = qkv + (size_t)b * 2048 * RS + h * 64;
    const unsigned short* Kb = Qb + 1024;
    const unsigned short* Vt = vT + (size_t)(b * 16 + h) * 64 * 2048;

    __shared__ __align__(16) unsigned short Ks[2][64 * 32];     // [dim-half][key][32 dims] 4KB ea
    __shared__ __align__(16) unsigned short Vs[2][64 * 32];     // [key-half][dim][32 keys] 4KB ea
    __shared__ __align__(16) unsigned short Ps[4][2 * 16 * 64]; // wave-private, 4KB ea

    short8 qf[2][2];
    int qrow0[2];
#pragma unroll
    for (int rg = 0; rg < 2; rg++) {
        int qt = (rg == 0) ? p : (31 - p);
        qrow0[rg] = qt * 64 + wave * 16;
        const unsigned short* qrow = Qb + (size_t)(qrow0[rg] + fr) * RS;
        qf[rg][0] = *(const short8*)(qrow + fq * 8);
        qf[rg][1] = *(const short8*)(qrow + 32 + fq * 8);
    }
    short8 ones;
#pragma unroll
    for (int e = 0; e < 8; e++) ones[e] = (short)0x3F80;

    f32x4 o_acc[2][4] = {};
    f32x4 l_acc[2] = {};

    const int grow = lane >> 2;
    // pre-swizzled global source column: LDS row r gets 8-dim block c at position
    // (c + (r>>1)) & 3 (wave row-offset 16w drops mod 4) — rule #21
    const int gswz = (((lane & 3) - (grow >> 1)) & 3) * 8;
    const unsigned short* Kg = Kb + (size_t)(wave * 16 + grow) * RS + gswz;
    const unsigned short* Vg = Vt + (size_t)(wave * 16 + grow) * 2048 + gswz;
    const int wb = wave * 16 * 32;   // wave's 16-row slice within each 64-row panel

    // per-lane LDS staging destinations (byte-identical to global_load_lds:
    // wave-uniform base + lane*16B)
    unsigned short* dK0 = Ks[0] + wb + lane * 8;
    unsigned short* dK1 = Ks[1] + wb + lane * 8;
    unsigned short* dV0 = Vs[0] + wb + lane * 8;
    unsigned short* dV1 = Vs[1] + wb + lane * 8;

    // full key range for this q-tile pair: tiles [0, 32-p). Work = 4(p+1)+2(31-2p)
    // = 66 units for EVERY p — perfectly balanced without a split.
    const int hi = 32 - p;

    // T14 prologue: load tile 0 into regs, write to LDS, sync
    {
        uint4v aK0 = *(const uint4v*)(Kg);
        uint4v aK1 = *(const uint4v*)(Kg + 32);
        uint4v aV0 = *(const uint4v*)(Vg);
        uint4v aV1 = *(const uint4v*)(Vg + 32);
        *(uint4v*)dK0 = aK0;
        *(uint4v*)dK1 = aK1;
        *(uint4v*)dV0 = aV0;
        *(uint4v*)dV1 = aV1;
    }
    __syncthreads();

    for (int jt = 0; jt < hi; jt++) {
        const int j0 = jt * 64;
        const bool more = (jt + 1 < hi);           // block-uniform
        const int j0n = more ? (j0 + 64) : j0;     // clamp: harmless reload on last

        // issue-early: prefetch tile jt+1 into registers (latency hides under compute)
        uint4v aK0 = *(const uint4v*)(Kg + (size_t)j0n * RS);
        uint4v aK1 = *(const uint4v*)(Kg + (size_t)j0n * RS + 32);
        uint4v aV0 = *(const uint4v*)(Vg + j0n);
        uint4v aV1 = *(const uint4v*)(Vg + j0n + 32); // keys j0n+32..+63

        bool diagA = (jt == p), diagB = (jt == 31 - p);
        if (jt <= p)
            attn_step<0>(Ks[0], Ks[1], Vs[0], Vs[1], Ps[wave], qf, ones,
                         o_acc, l_acc, j0, fr, fq, qrow0, diagA, diagB);
        else
            attn_step<1>(Ks[0], Ks[1], Vs[0], Vs[1], Ps[wave], qf, ones,
                         o_acc, l_acc, j0, fr, fq, qrow0, diagA, diagB);

        __syncthreads();                 // all waves done READING current tile
        if (more) {                      // write-late: prefetched tile into LDS
            *(uint4v*)dK0 = aK0;
            *(uint4v*)dK1 = aK1;
            *(uint4v*)dV0 = aV0;
            *(uint4v*)dV1 = aV1;
        }
        __syncthreads();                 // writes visible to all waves
    }

    // normalize by full softmax denominator and write final attn (bf16)
#pragma unroll
    for (int rg = 0; rg < 2; rg++) {
        float inv[4];
#pragma unroll
        for (int r = 0; r < 4; r++)
            inv[r] = 1.0f / l_acc[rg][r];
#pragma unroll
        for (int t = 0; t < 4; t++)
#pragma unroll
            for (int r = 0; r < 4; r++) {
                int row = qrow0[rg] + fq * 4 + r;
                attn[(size_t)(b * 2048 + row) * 1024 + h * 64 + t * 16 + fr] =
                    f2bf(o_acc[rg][t][r] * inv[r]);
            }
    }
}

// ----------------------------------------------------------------
extern "C" void kernel_launch(void* const* d_in, const int* in_sizes, int n_in,
                              void* d_out, int out_size, void* d_ws, size_t ws_size,
                              hipStream_t stream) {
    const float* x      = (const float*)d_in[0];
    const float* w_qkv  = (const float*)d_in[1];
    const float* b_qkv  = (const float*)d_in[2];
    const float* w_out  = (const float*)d_in[3];
    const float* b_out  = (const float*)d_in[4];
    float* out = (float*)d_out;

    char* ws = (char*)d_ws;
    unsigned short* x_b    = (unsigned short*)(ws);                        //  8 MB
    unsigned short* wqkv_t = (unsigned short*)(ws + 8u  * 1024 * 1024);    //  6 MB
    unsigned short* wout_t = (unsigned short*)(ws + 14u * 1024 * 1024);    //  2 MB
    unsigned short* qkv    = (unsigned short*)(ws + 16u * 1024 * 1024);    // 16 MB (Q|K stride 2048)
    unsigned short* attn   = (unsigned short*)(ws + 32u * 1024 * 1024);    //  8 MB
    unsigned short* vT     = (unsigned short*)(ws + 40u * 1024 * 1024);    //  8 MB

    prep<<<5120, 256, 0, stream>>>(x, w_qkv, w_out, x_b, wqkv_t, wout_t);
    gemm_bt<true, true ><<<dim3(32, 24), 256, 0, stream>>>(x_b,  wqkv_t, b_qkv, qkv, vT, 4096, 3072, 1024);
    flash_attn<<<dim3(16, 32), 256, 0, stream>>>(qkv, vT, attn);
    gemm_bt<false, false><<<dim3(32, 8),  256, 0, stream>>>(attn, wout_t, b_out, out, nullptr, 4096, 1024, 1024);
}

// Round 15
// 172.224 us; speedup vs baseline: 1.0540x; 1.0540x over previous
//
#include <hip/hip_runtime.h>
#include <hip/hip_bf16.h>

typedef short short8 __attribute__((ext_vector_type(8)));
typedef float f32x4 __attribute__((ext_vector_type(4)));
typedef unsigned int uint4v __attribute__((ext_vector_type(4)));

typedef const __attribute__((address_space(1))) unsigned int* gas_ptr;
typedef __attribute__((address_space(3))) unsigned int* las_ptr;
// async global->LDS, 16B/lane; LDS dest = wave-uniform base + lane*16 (m97/m104)
#define ASYNC16(g, l) __builtin_amdgcn_global_load_lds((gas_ptr)(g), (las_ptr)(l), 16, 0, 0)

__device__ __forceinline__ unsigned short f2bf(float f) {
    unsigned int u = __builtin_bit_cast(unsigned int, f);
    u += 0x7fff + ((u >> 16) & 1);   // RNE
    return (unsigned short)(u >> 16);
}
__device__ __forceinline__ float bf2f(unsigned short s) {
    unsigned int u = (unsigned int)s << 16;
    return __builtin_bit_cast(float, u);
}
__device__ __forceinline__ unsigned int pkbf_trunc(float lo, float hi) {
    return __builtin_amdgcn_perm(__builtin_bit_cast(unsigned int, hi),
                                 __builtin_bit_cast(unsigned int, lo), 0x07060302u);
}
__device__ __forceinline__ float fexp2(float x) {
#if __has_builtin(__builtin_amdgcn_exp2f)
    return __builtin_amdgcn_exp2f(x);
#else
    return __expf(x * 0.6931471805599453f);
#endif
}

// ---------------------------------------------------------------- fused prep (r10):
// blocks [0,4096): cast x->bf16 ; [4096,4864): transpose w_qkv ; [4864,5120): transpose w_out
// (r11/r12 lesson: fusing elementwise work into GEMM staging re-inserts latency into
// every k-step x 1/occupancy — standalone memory-bound passes are cheaper.)
__device__ __forceinline__ void transpose_tile(
    const float* __restrict__ w, unsigned short* __restrict__ wt,
    int K, int N, int k0, int n0, unsigned short* tile)
{
    for (int i = threadIdx.x; i < 64 * 64; i += 256) {
        int r = i >> 6, c = i & 63;
        tile[r * 65 + c] = f2bf(w[(size_t)(k0 + r) * N + n0 + c]);
    }
    __syncthreads();
    for (int i = threadIdx.x; i < 64 * 64; i += 256) {
        int r = i >> 6, c = i & 63;
        wt[(size_t)(n0 + r) * K + k0 + c] = tile[c * 65 + r];
    }
}

__global__ __launch_bounds__(256) void prep(
    const float* __restrict__ x, const float* __restrict__ w_qkv,
    const float* __restrict__ w_out,
    unsigned short* __restrict__ x_b, unsigned short* __restrict__ wqkv_t,
    unsigned short* __restrict__ wout_t)
{
    __shared__ unsigned short tile[64 * 65];
    int bid = blockIdx.x;
    if (bid < 4096) {
        int i = (bid * 256 + threadIdx.x) * 4;
        float4 v = *(const float4*)(x + i);
        ushort4 o;
        o.x = f2bf(v.x); o.y = f2bf(v.y); o.z = f2bf(v.z); o.w = f2bf(v.w);
        *(ushort4*)(x_b + i) = o;
    } else if (bid < 4096 + 768) {
        int t = bid - 4096;
        transpose_tile(w_qkv, wqkv_t, 1024, 3072, (t / 48) * 64, (t % 48) * 64, tile);
    } else {
        int t = bid - 4864;
        transpose_tile(w_out, wout_t, 1024, 1024, (t >> 4) * 64, (t & 15) * 64, tile);
    }
}

// ---------------------------------------------------------------- GEMM: C = A * Bt^T + bias
// m97 structure, BK=64 via twin 8KB panels (r4: verified-good).
// NO XCD swizzle (r14: −7 µs — all operands L3-fit, swizzle costs ~2% in that
// regime per catalog m160 and perturbs dispatch balance). QKV mode:
// cols [0,2048) -> qkv (stride 2048); cols [2048,3072) -> vT

template<bool OUT_BF16, bool QKV>
__global__ __launch_bounds__(256, 3) void gemm_bt(
    const unsigned short* __restrict__ A,
    const unsigned short* __restrict__ Bt,
    const float* __restrict__ bias,
    void* __restrict__ C,
    unsigned short* __restrict__ vTp,
    int M, int N, int K)
{
    __shared__ __align__(16) unsigned short As[2][128 * 32];
    __shared__ __align__(16) unsigned short Bs[2][128 * 32];
    const int tid = threadIdx.x;
    const int lane = tid & 63;
    const int wave = tid >> 6;
    const int wr = wave >> 1, wc = wave & 1;
    const int m0 = blockIdx.x * 128, n0 = blockIdx.y * 128;
    const int fr = lane & 15, fq = lane >> 4;

    f32x4 acc[4][4] = {};

    const int grow = lane >> 2;
    const int gcol = (lane & 3) * 8;
    const unsigned short* Ag = A  + (size_t)(m0 + wave * 32 + grow) * K + gcol;
    const unsigned short* Bg = Bt + (size_t)(n0 + wave * 32 + grow) * K + gcol;
    const int wb0 = (wave * 32) * 32;
    const int wb1 = (wave * 32 + 16) * 32;

    for (int k0 = 0; k0 < K; k0 += 64) {
        __syncthreads();
        ASYNC16(Ag + k0,               As[0] + wb0);
        ASYNC16(Ag + 16 * K + k0,      As[0] + wb1);
        ASYNC16(Bg + k0,               Bs[0] + wb0);
        ASYNC16(Bg + 16 * K + k0,      Bs[0] + wb1);
        ASYNC16(Ag + k0 + 32,          As[1] + wb0);
        ASYNC16(Ag + 16 * K + k0 + 32, As[1] + wb1);
        ASYNC16(Bg + k0 + 32,          Bs[1] + wb0);
        ASYNC16(Bg + 16 * K + k0 + 32, Bs[1] + wb1);
        __syncthreads();

#pragma unroll
        for (int h = 0; h < 2; h++) {
            short8 af[4], bfr[4];
#pragma unroll
            for (int i = 0; i < 4; i++)
                af[i] = *(const short8*)(As[h] + (wr * 64 + i * 16 + fr) * 32 + fq * 8);
#pragma unroll
            for (int j = 0; j < 4; j++)
                bfr[j] = *(const short8*)(Bs[h] + (wc * 64 + j * 16 + fr) * 32 + fq * 8);
#pragma unroll
            for (int i = 0; i < 4; i++)
#pragma unroll
                for (int j = 0; j < 4; j++)
                    acc[i][j] = __builtin_amdgcn_mfma_f32_16x16x32_bf16(af[i], bfr[j], acc[i][j], 0, 0, 0);
        }
    }

#pragma unroll
    for (int i = 0; i < 4; i++)
#pragma unroll
        for (int j = 0; j < 4; j++) {
            int col = n0 + wc * 64 + j * 16 + fr;
            float bv = bias[col];
            if (QKV && col >= 2048) {
                int hh = (col - 2048) >> 6, d = col & 63;
#pragma unroll
                for (int r = 0; r < 4; r++) {
                    int row = m0 + wr * 64 + i * 16 + fq * 4 + r;
                    int bb = row >> 11, s = row & 2047;
                    vTp[((size_t)(bb * 16 + hh) * 64 + d) * 2048 + s] = f2bf(acc[i][j][r] + bv);
                }
            } else {
                const int cstride = QKV ? 2048 : N;
#pragma unroll
                for (int r = 0; r < 4; r++) {
                    int row = m0 + wr * 64 + i * 16 + fq * 4 + r;
                    float v = acc[i][j][r] + bv;
                    if (OUT_BF16)
                        ((unsigned short*)C)[(size_t)row * cstride + col] = f2bf(v);
                    else
                        ((float*)C)[(size_t)row * cstride + col] = v;
                }
            }
        }
}

// ---------------------------------------------------------------- flash attention (causal, NO key-split)
// Round-15 = round-13 verbatim (174.3 µs, best verified; r14's XCD swizzle was
// −7 µs — L3-fit regime, reverted).
// Each block covers ALL keys for its balanced q-tile pair {p, 31-p}: work =
// 4(p+1) + 2(31-2p) = 66 weighted units for EVERY p. Grid = 512 equal-work
// blocks = exactly 2/CU, all resident from t=0, zero tail. Block owns the full
// softmax denominator -> normalize in-regs and write final attn directly
// (no reduce_attn, no Opart/lpart traffic).
// Structure (verified r10/r13): 4-wave 256-thread blocks, 64-key tile, 32 KB LDS,
// launch bound (256,2), T14 async-STAGE split (issue-early regs / write-late LDS).
// Wave w owns 32 q-rows: rg0 = q-tile p rows [w*16,+16); rg1 = q-tile 31-p rows.
// Swapped QK^T (lane holds 4 consecutive keys of one q-row; P store = one b64),
// bijective P swizzle, K/V global-source pre-swizzle (rule #21), setprio,
// exp2-folded fixed-shift softmax p=exp(s/8-8).

template<int RG0>   // 0: both rg active; 1: only rg1 (jt > p)
__device__ __forceinline__ void attn_step(
    const unsigned short* __restrict__ Ks0, const unsigned short* __restrict__ Ks1,
    const unsigned short* __restrict__ Vs0, const unsigned short* __restrict__ Vs1,
    unsigned short* __restrict__ Psw,
    const short8 (&qf)[2][2], const short8 ones,
    f32x4 (&o_acc)[2][4], f32x4 (&l_acc)[2],
    int j0, int fr, int fq,
    const int (&qrow0)[2], bool diagA, bool diagB)
{
    const int kpos = ((fq + (fr >> 1)) & 3) * 8;   // K/V bank-position (matches staging swizzle)
    short8 kf[4][2];
#pragma unroll
    for (int t = 0; t < 4; t++) {
        kf[t][0] = *(const short8*)(Ks0 + (t * 16 + fr) * 32 + kpos);
        kf[t][1] = *(const short8*)(Ks1 + (t * 16 + fr) * 32 + kpos);
    }

    const float C1 = 0.18033688011112042f;   // 0.125 * log2(e)
    const float C2 = -11.541560327111707f;   // -8 * log2(e)

#pragma unroll
    for (int rg = RG0; rg < 2; rg++) {
        f32x4 s[4];
        __builtin_amdgcn_s_setprio(1);
#pragma unroll
        for (int t = 0; t < 4; t++) {
            s[t] = (f32x4){0.f, 0.f, 0.f, 0.f};
            s[t] = __builtin_amdgcn_mfma_f32_16x16x32_bf16(kf[t][0], qf[rg][0], s[t], 0, 0, 0);
            s[t] = __builtin_amdgcn_mfma_f32_16x16x32_bf16(kf[t][1], qf[rg][1], s[t], 0, 0, 0);
        }
        __builtin_amdgcn_s_setprio(0);
        const bool diag = (rg == 0) ? diagA : diagB;
        unsigned short* prow = Psw + rg * (16 * 64);
        const int qr = qrow0[rg] + fr;
        if (diag) {   // wave-uniform branch: mask cost only on diag tiles
#pragma unroll
            for (int t = 0; t < 4; t++) {
                const int kb = j0 + t * 16 + fq * 4;
                float p[4];
#pragma unroll
                for (int r = 0; r < 4; r++) {
                    float v = fexp2(s[t][r] * C1 + C2);
                    if (kb + r > qr) v = 0.f;
                    p[r] = v;
                }
                uint2 pk;
                pk.x = pkbf_trunc(p[0], p[1]);
                pk.y = pkbf_trunc(p[2], p[3]);
                const int blk = (t * 2 + (fq >> 1) + fr) & 7;
                *(uint2*)(prow + fr * 64 + blk * 8 + (fq & 1) * 4) = pk;
            }
        } else {
#pragma unroll
            for (int t = 0; t < 4; t++) {
                float p[4];
#pragma unroll
                for (int r = 0; r < 4; r++)
                    p[r] = fexp2(s[t][r] * C1 + C2);
                uint2 pk;
                pk.x = pkbf_trunc(p[0], p[1]);
                pk.y = pkbf_trunc(p[2], p[3]);
                const int blk = (t * 2 + (fq >> 1) + fr) & 7;
                *(uint2*)(prow + fr * 64 + blk * 8 + (fq & 1) * 4) = pk;
            }
        }
    }

    // O += P V ; l += P 1   (Psw wave-private: same-wave LDS ordering, no barrier)
#pragma unroll
    for (int ks = 0; ks < 2; ks++) {
        const unsigned short* Vsb = ks ? Vs1 : Vs0;
        const int colp = ((ks * 4 + fq + fr) & 7) * 8;   // P bank-position unswizzle
        short8 pf[2];
#pragma unroll
        for (int rg = RG0; rg < 2; rg++)
            pf[rg] = *(const short8*)(Psw + rg * (16 * 64) + fr * 64 + colp);
        __builtin_amdgcn_s_setprio(1);
#pragma unroll
        for (int t = 0; t < 4; t++) {
            short8 vf = *(const short8*)(Vsb + (t * 16 + fr) * 32 + kpos);
#pragma unroll
            for (int rg = RG0; rg < 2; rg++)
                o_acc[rg][t] = __builtin_amdgcn_mfma_f32_16x16x32_bf16(pf[rg], vf, o_acc[rg][t], 0, 0, 0);
        }
#pragma unroll
        for (int rg = RG0; rg < 2; rg++)
            l_acc[rg] = __builtin_amdgcn_mfma_f32_16x16x32_bf16(pf[rg], ones, l_acc[rg], 0, 0, 0);
        __builtin_amdgcn_s_setprio(0);
    }
}

__global__ __launch_bounds__(256, 2) void flash_attn(
    const unsigned short* __restrict__ qkv,   // (B*S, 2048): Q | K
    const unsigned short* __restrict__ vT,    // (B*16 heads, 64 dims, 2048 keys)
    unsigned short* __restrict__ attn)        // (B*S, 1024) final normalized O
{
    const int p = blockIdx.x;                 // q-tile pair {p, 31-p}
    const int h = blockIdx.y & 15, b = blockIdx.y >> 4;
    const int tid = threadIdx.x, wave = tid >> 6, lane = tid & 63;
    const int fr = lane & 15, fq = lane >> 4;
    const size_t RS = 2048;

    const unsigned short* Qb = qkv + (size_t)b * 2048 * RS + h * 64;
    const unsigned short* Kb = Qb + 1024;
    const unsigned short* Vt = vT + (size_t)(b * 16 + h) * 64 * 2048;

    __shared__ __align__(16) unsigned short Ks[2][64 * 32];     // [dim-half][key][32 dims] 4KB ea
    __shared__ __align__(16) unsigned short Vs[2][64 * 32];     // [key-half][dim][32 keys] 4KB ea
    __shared__ __align__(16) unsigned short Ps[4][2 * 16 * 64]; // wave-private, 4KB ea

    short8 qf[2][2];
    int qrow0[2];
#pragma unroll
    for (int rg = 0; rg < 2; rg++) {
        int qt = (rg == 0) ? p : (31 - p);
        qrow0[rg] = qt * 64 + wave * 16;
        const unsigned short* qrow = Qb + (size_t)(qrow0[rg] + fr) * RS;
        qf[rg][0] = *(const short8*)(qrow + fq * 8);
        qf[rg][1] = *(const short8*)(qrow + 32 + fq * 8);
    }
    short8 ones;
#pragma unroll
    for (int e = 0; e < 8; e++) ones[e] = (short)0x3F80;

    f32x4 o_acc[2][4] = {};
    f32x4 l_acc[2] = {};

    const int grow = lane >> 2;
    // pre-swizzled global source column: LDS row r gets 8-dim block c at position
    // (c + (r>>1)) & 3 (wave row-offset 16w drops mod 4) — rule #21
    const int gswz = (((lane & 3) - (grow >> 1)) & 3) * 8;
    const unsigned short* Kg = Kb + (size_t)(wave * 16 + grow) * RS + gswz;
    const unsigned short* Vg = Vt + (size_t)(wave * 16 + grow) * 2048 + gswz;
    const int wb = wave * 16 * 32;   // wave's 16-row slice within each 64-row panel

    // per-lane LDS staging destinations (byte-identical to global_load_lds:
    // wave-uniform base + lane*16B)
    unsigned short* dK0 = Ks[0] + wb + lane * 8;
    unsigned short* dK1 = Ks[1] + wb + lane * 8;
    unsigned short* dV0 = Vs[0] + wb + lane * 8;
    unsigned short* dV1 = Vs[1] + wb + lane * 8;

    // full key range for this q-tile pair: tiles [0, 32-p). Work = 4(p+1)+2(31-2p)
    // = 66 units for EVERY p — perfectly balanced without a split.
    const int hi = 32 - p;

    // T14 prologue: load tile 0 into regs, write to LDS, sync
    {
        uint4v aK0 = *(const uint4v*)(Kg);
        uint4v aK1 = *(const uint4v*)(Kg + 32);
        uint4v aV0 = *(const uint4v*)(Vg);
        uint4v aV1 = *(const uint4v*)(Vg + 32);
        *(uint4v*)dK0 = aK0;
        *(uint4v*)dK1 = aK1;
        *(uint4v*)dV0 = aV0;
        *(uint4v*)dV1 = aV1;
    }
    __syncthreads();

    for (int jt = 0; jt < hi; jt++) {
        const int j0 = jt * 64;
        const bool more = (jt + 1 < hi);           // block-uniform
        const int j0n = more ? (j0 + 64) : j0;     // clamp: harmless reload on last

        // issue-early: prefetch tile jt+1 into registers (latency hides under compute)
        uint4v aK0 = *(const uint4v*)(Kg + (size_t)j0n * RS);
        uint4v aK1 = *(const uint4v*)(Kg + (size_t)j0n * RS + 32);
        uint4v aV0 = *(const uint4v*)(Vg + j0n);
        uint4v aV1 = *(const uint4v*)(Vg + j0n + 32); // keys j0n+32..+63

        bool diagA = (jt == p), diagB = (jt == 31 - p);
        if (jt <= p)
            attn_step<0>(Ks[0], Ks[1], Vs[0], Vs[1], Ps[wave], qf, ones,
                         o_acc, l_acc, j0, fr, fq, qrow0, diagA, diagB);
        else
            attn_step<1>(Ks[0], Ks[1], Vs[0], Vs[1], Ps[wave], qf, ones,
                         o_acc, l_acc, j0, fr, fq, qrow0, diagA, diagB);

        __syncthreads();                 // all waves done READING current tile
        if (more) {                      // write-late: prefetched tile into LDS
            *(uint4v*)dK0 = aK0;
            *(uint4v*)dK1 = aK1;
            *(uint4v*)dV0 = aV0;
            *(uint4v*)dV1 = aV1;
        }
        __syncthreads();                 // writes visible to all waves
    }

    // normalize by full softmax denominator and write final attn (bf16)
#pragma unroll
    for (int rg = 0; rg < 2; rg++) {
        float inv[4];
#pragma unroll
        for (int r = 0; r < 4; r++)
            inv[r] = 1.0f / l_acc[rg][r];
#pragma unroll
        for (int t = 0; t < 4; t++)
#pragma unroll
            for (int r = 0; r < 4; r++) {
                int row = qrow0[rg] + fq * 4 + r;
                attn[(size_t)(b * 2048 + row) * 1024 + h * 64 + t * 16 + fr] =
                    f2bf(o_acc[rg][t][r] * inv[r]);
            }
    }
}

// ----------------------------------------------------------------
extern "C" void kernel_launch(void* const* d_in, const int* in_sizes, int n_in,
                              void* d_out, int out_size, void* d_ws, size_t ws_size,
                              hipStream_t stream) {
    const float* x      = (const float*)d_in[0];
    const float* w_qkv  = (const float*)d_in[1];
    const float* b_qkv  = (const float*)d_in[2];
    const float* w_out  = (const float*)d_in[3];
    const float* b_out  = (const float*)d_in[4];
    float* out = (float*)d_out;

    char* ws = (char*)d_ws;
    unsigned short* x_b    = (unsigned short*)(ws);                        //  8 MB
    unsigned short* wqkv_t = (unsigned short*)(ws + 8u  * 1024 * 1024);    //  6 MB
    unsigned short* wout_t = (unsigned short*)(ws + 14u * 1024 * 1024);    //  2 MB
    unsigned short* qkv    = (unsigned short*)(ws + 16u * 1024 * 1024);    // 16 MB (Q|K stride 2048)
    unsigned short* attn   = (unsigned short*)(ws + 32u * 1024 * 1024);    //  8 MB
    unsigned short* vT     = (unsigned short*)(ws + 40u * 1024 * 1024);    //  8 MB

    prep<<<5120, 256, 0, stream>>>(x, w_qkv, w_out, x_b, wqkv_t, wout_t);
    gemm_bt<true, true ><<<dim3(32, 24), 256, 0, stream>>>(x_b,  wqkv_t, b_qkv, qkv, vT, 4096, 3072, 1024);
    flash_attn<<<dim3(16, 32), 256, 0, stream>>>(qkv, vT, attn);
    gemm_bt<false, false><<<dim3(32, 8),  256, 0, stream>>>(attn, wout_t, b_out, out, nullptr, 4096, 1024, 1024);
}